// Round 1
// 91.288 us; speedup vs baseline: 1.0210x; 1.0210x over previous
//
#include <hip/hip_runtime.h>

#define SEQ 256
#define NCHUNK 4                      // key-split factor
#define CHUNK (SEQ / NCHUNK)          // 64 keys per thread
#define NTHREADS (SEQ * NCHUNK)       // 1024 threads = 16 waves/block
#define LOG2E 1.44269504088896340736f

// min 8 waves/EU -> VGPR<=64 -> 2 blocks/CU resident = 32 waves/CU (full)
__global__ __launch_bounds__(NTHREADS, 8) void pico_transformer_kernel(
    const float* __restrict__ x,      // [B,S]
    const float* __restrict__ emb_w,  // [4,1]
    const float* __restrict__ emb_b,  // [4]
    const float* __restrict__ q_w,    // [4,4]
    const float* __restrict__ q_b,    // [4]
    const float* __restrict__ k_w,    // [4,4]
    const float* __restrict__ k_b,    // [4]
    const float* __restrict__ v_w,    // [4,4]
    const float* __restrict__ v_b,    // [4]
    const float* __restrict__ f1_w,   // [8,4]
    const float* __restrict__ f1_b,   // [8]
    const float* __restrict__ f2_w,   // [1,8]
    const float* __restrict__ f2_b,   // [1]
    float* __restrict__ out)          // [B]
{
    __shared__ float xs[SEQ];
    __shared__ float consts[27];   // [0]=c1*log2e [1]=c3*log2e [2..9]=u [10..17]=w [18..25]=f2w [26]=f2b
    __shared__ float red_mx[4], red_mn[4], red_sum[4];
    __shared__ float num_part[NCHUNK][SEQ];
    __shared__ float den_part[NCHUNK][SEQ];

    const int tid = threadIdx.x;
    const int b   = blockIdx.x;
    const int q   = tid & (SEQ - 1);  // query index (per-lane)
    const int c   = tid >> 8;         // key chunk (wave-uniform: 4 waves per chunk)

    // Waves 0-3: stage the x row + row max/min reduce.
    if (tid < SEQ) {
        float xv = x[b * SEQ + tid];
        xs[tid] = xv;
        float mx = xv, mn = xv;
        #pragma unroll
        for (int off = 32; off > 0; off >>= 1) {
            mx = fmaxf(mx, __shfl_down(mx, off, 64));
            mn = fminf(mn, __shfl_down(mn, off, 64));
        }
        if ((tid & 63) == 0) { red_mx[tid >> 6] = mx; red_mn[tid >> 6] = mn; }
    }

    // Thread 0 folds the tiny weight stack into 27 scalars (L2-warm after
    // the first blocks; overlaps with the staging waves above).
    if (tid == 0) {
        float we[4], be[4], Aq[4], Bq[4], Ak[4], Av[4], Bv[4];
        #pragma unroll
        for (int d = 0; d < 4; ++d) { we[d] = emb_w[d]; be[d] = emb_b[d]; }
        #pragma unroll
        for (int e = 0; e < 4; ++e) {
            float aq = 0.f, bq = 0.f, ak = 0.f, av = 0.f, bv = 0.f;
            #pragma unroll
            for (int d = 0; d < 4; ++d) {
                aq += q_w[e*4+d] * we[d];
                bq += q_w[e*4+d] * be[d];
                ak += k_w[e*4+d] * we[d];
                av += v_w[e*4+d] * we[d];
                bv += v_w[e*4+d] * be[d];
            }
            Aq[e] = aq; Bq[e] = bq + q_b[e]; Ak[e] = ak;
            Av[e] = av; Bv[e] = bv + v_b[e];
        }
        float c1 = 0.f, c3 = 0.f;
        #pragma unroll
        for (int d = 0; d < 4; ++d) { c1 += Aq[d]*Ak[d]; c3 += Bq[d]*Ak[d]; }
        consts[0] = 0.5f * c1 * LOG2E;   // temperature slope (log2 domain)
        consts[1] = 0.5f * c3 * LOG2E;   // temperature offset
        #pragma unroll
        for (int j = 0; j < 8; ++j) {
            float u = 0.f, w = 0.f;
            #pragma unroll
            for (int d = 0; d < 4; ++d) {
                u += f1_w[j*4+d] * Av[d];
                w += f1_w[j*4+d] * Bv[d];
            }
            consts[2 + j]  = u;
            consts[10 + j] = w + f1_b[j];
            consts[18 + j] = f2_w[j];
        }
        consts[26] = f2_b[0];
    }

    __syncthreads();  // covers xs, consts, red_mx/red_mn

    const float XMAX = fmaxf(fmaxf(red_mx[0], red_mx[1]), fmaxf(red_mx[2], red_mx[3]));
    const float XMIN = fminf(fminf(red_mn[0], red_mn[1]), fminf(red_mn[2], red_mn[3]));

    // Per-query temperature (log2 domain) and its exact row max
    // (max_j t*x_j = t>=0 ? t*xmax : t*xmin).
    const float xq  = xs[q];                      // lanes contiguous: conflict-free
    const float t2  = consts[0] * xq + consts[1];
    const float m2  = (t2 >= 0.f) ? t2 * XMAX : t2 * XMIN;
    const float nm2 = -m2;

    // Partial g over this thread's 64-key chunk. All lanes of a wave share c
    // -> same LDS address per iter -> broadcast, no conflicts.
    // Dual accumulators break the fma dependency chain.
    float num0 = 0.f, num1 = 0.f, den0 = 0.f, den1 = 0.f;
    const float4* xs4 = (const float4*)xs + c * (CHUNK / 4);
    #pragma unroll 4
    for (int j4 = 0; j4 < CHUNK / 4; ++j4) {
        float4 xk = xs4[j4];
        float e0 = __builtin_amdgcn_exp2f(fmaf(t2, xk.x, nm2));
        float e1 = __builtin_amdgcn_exp2f(fmaf(t2, xk.y, nm2));
        float e2 = __builtin_amdgcn_exp2f(fmaf(t2, xk.z, nm2));
        float e3 = __builtin_amdgcn_exp2f(fmaf(t2, xk.w, nm2));
        num0 = fmaf(xk.x, e0, num0);
        num1 = fmaf(xk.y, e1, num1);
        num0 = fmaf(xk.z, e2, num0);
        num1 = fmaf(xk.w, e3, num1);
        den0 += e0 + e2;
        den1 += e1 + e3;
    }
    num_part[c][q] = num0 + num1;   // per wave: c uniform, q contiguous -> conflict-free
    den_part[c][q] = den0 + den1;

    __syncthreads();

    // Waves 0-3: combine the 4 chunk partials per query, g = num/den, mean over queries.
    if (tid < SEQ) {
        float n = (num_part[0][tid] + num_part[1][tid]) + (num_part[2][tid] + num_part[3][tid]);
        float d = (den_part[0][tid] + den_part[1][tid]) + (den_part[2][tid] + den_part[3][tid]);
        float g = n / d;
        #pragma unroll
        for (int off = 32; off > 0; off >>= 1) g += __shfl_down(g, off, 64);
        if ((tid & 63) == 0) red_sum[tid >> 6] = g;
    }
    __syncthreads();

    if (tid == 0) {
        float G = (red_sum[0] + red_sum[1] + red_sum[2] + red_sum[3]) * (1.0f / SEQ);
        float acc = consts[26];
        #pragma unroll
        for (int j = 0; j < 8; ++j) {
            float hv = fmaxf(G * consts[2 + j] + consts[10 + j], 0.f);
            acc += hv * consts[18 + j];
        }
        out[b] = acc;
    }
}

extern "C" void kernel_launch(void* const* d_in, const int* in_sizes, int n_in,
                              void* d_out, int out_size, void* d_ws, size_t ws_size,
                              hipStream_t stream) {
    const float* x     = (const float*)d_in[0];
    const float* emb_w = (const float*)d_in[1];
    const float* emb_b = (const float*)d_in[2];
    const float* q_w   = (const float*)d_in[3];
    const float* q_b   = (const float*)d_in[4];
    const float* k_w   = (const float*)d_in[5];
    const float* k_b   = (const float*)d_in[6];
    const float* v_w   = (const float*)d_in[7];
    const float* v_b   = (const float*)d_in[8];
    const float* f1_w  = (const float*)d_in[9];
    const float* f1_b  = (const float*)d_in[10];
    const float* f2_w  = (const float*)d_in[11];
    const float* f2_b  = (const float*)d_in[12];
    float* out = (float*)d_out;

    const int B = in_sizes[0] / SEQ;   // 1024
    pico_transformer_kernel<<<B, NTHREADS, 0, stream>>>(
        x, emb_w, emb_b, q_w, q_b, k_w, k_b, v_w, v_b,
        f1_w, f1_b, f2_w, f2_b, out);
}

// Round 2
// 85.677 us; speedup vs baseline: 1.0879x; 1.0655x over previous
//
#include <hip/hip_runtime.h>

#define SEQ 256
#define ROWS 2                        // batch rows per block
#define KCH 32                        // Chebyshev nodes / terms
#define NTHREADS 1024
#define LOG2E 1.44269504088896340736f

// 16 waves/block; min 8 waves/EU -> VGPR<=64 -> 2 blocks/CU co-resident.
__global__ __launch_bounds__(NTHREADS, 8) void pico_transformer_kernel(
    const float* __restrict__ x,      // [B,S]
    const float* __restrict__ emb_w,  // [4,1]
    const float* __restrict__ emb_b,  // [4]
    const float* __restrict__ q_w,    // [4,4]
    const float* __restrict__ q_b,    // [4]
    const float* __restrict__ k_w,    // [4,4]
    const float* __restrict__ k_b,    // [4]
    const float* __restrict__ v_w,    // [4,4]
    const float* __restrict__ v_b,    // [4]
    const float* __restrict__ f1_w,   // [8,4]
    const float* __restrict__ f1_b,   // [8]
    const float* __restrict__ f2_w,   // [1,8]
    const float* __restrict__ f2_b,   // [1]
    float* __restrict__ out)          // [B]
{
    __shared__ float xs[ROWS][SEQ];
    __shared__ float cons[27];  // [0]=a(log2) [1]=b(log2) [2..9]=u [10..17]=w [18..25]=f2w [26]=f2b
    __shared__ float red_mx[8], red_mn[8];      // per-wave row min/max partials
    __shared__ float gnode[ROWS][KCH];          // g at Chebyshev nodes
    __shared__ float coef[ROWS][KCH];           // Chebyshev coefficients (scaled)
    __shared__ float mids[ROWS], radinvs[ROWS];
    __shared__ float red_sum[8];

    const int tid = threadIdx.x;
    const int blk = blockIdx.x;

    // ---- P1: stage 2 rows of x, per-row min/max, thread-0 weight fold ----
    if (tid < ROWS * SEQ) {
        const int r   = tid >> 8;
        const int col = tid & 255;
        float xv = x[(blk * ROWS + r) * SEQ + col];
        xs[r][col] = xv;
        float mx = xv, mn = xv;
        #pragma unroll
        for (int off = 32; off > 0; off >>= 1) {
            mx = fmaxf(mx, __shfl_down(mx, off, 64));
            mn = fminf(mn, __shfl_down(mn, off, 64));
        }
        if ((tid & 63) == 0) { red_mx[tid >> 6] = mx; red_mn[tid >> 6] = mn; }
    }

    if (tid == 0) {
        // Fold the tiny weight stack into 27 scalars (verbatim-known-good).
        float we[4], be[4], Aq[4], Bq[4], Ak[4], Av[4], Bv[4];
        #pragma unroll
        for (int d = 0; d < 4; ++d) { we[d] = emb_w[d]; be[d] = emb_b[d]; }
        #pragma unroll
        for (int e = 0; e < 4; ++e) {
            float aq = 0.f, bq = 0.f, ak = 0.f, av = 0.f, bv = 0.f;
            #pragma unroll
            for (int d = 0; d < 4; ++d) {
                aq += q_w[e*4+d] * we[d];
                bq += q_w[e*4+d] * be[d];
                ak += k_w[e*4+d] * we[d];
                av += v_w[e*4+d] * we[d];
                bv += v_w[e*4+d] * be[d];
            }
            Aq[e] = aq; Bq[e] = bq + q_b[e]; Ak[e] = ak;
            Av[e] = av; Bv[e] = bv + v_b[e];
        }
        float c1 = 0.f, c3 = 0.f;
        #pragma unroll
        for (int d = 0; d < 4; ++d) { c1 += Aq[d]*Ak[d]; c3 += Bq[d]*Ak[d]; }
        cons[0] = 0.5f * c1 * LOG2E;   // temperature slope (log2 domain), incl 1/sqrt(d)
        cons[1] = 0.5f * c3 * LOG2E;   // temperature offset
        #pragma unroll
        for (int j = 0; j < 8; ++j) {
            float u = 0.f, w = 0.f;
            #pragma unroll
            for (int d = 0; d < 4; ++d) {
                u += f1_w[j*4+d] * Av[d];
                w += f1_w[j*4+d] * Bv[d];
            }
            cons[2 + j]  = u;
            cons[10 + j] = w + f1_b[j];
            cons[18 + j] = f2_w[j];
        }
        cons[26] = f2_b[0];
    }

    __syncthreads();  // xs, cons, red_mx/red_mn

    // ---- P2: evaluate g(t) exactly at 32 Chebyshev-Gauss nodes per row ----
    // thread -> (row r, node i, key-slice s): 16 keys per thread.
    {
        const int r = tid >> 9;
        const int i = (tid >> 4) & 31;
        const int s = tid & 15;

        const int rb = r << 2;
        const float XMAX = fmaxf(fmaxf(red_mx[rb], red_mx[rb+1]), fmaxf(red_mx[rb+2], red_mx[rb+3]));
        const float XMIN = fminf(fminf(red_mn[rb], red_mn[rb+1]), fminf(red_mn[rb+2], red_mn[rb+3]));

        const float c0  = cons[0], c1v = cons[1];
        const float mid = fmaf(c0, 0.5f * (XMAX + XMIN), c1v);
        const float rad = fabsf(c0) * 0.5f * (XMAX - XMIN);

        // node temperature t_i = mid + rad*cos(pi*(i+0.5)/K)  (exact t-range cover)
        const float tau_i = cospif((float)(2 * i + 1) * (1.0f / 64.0f));
        const float t     = fmaf(rad, tau_i, mid);
        const float m2    = (t >= 0.f) ? t * XMAX : t * XMIN;  // exact row max of t*x
        const float nm2   = -m2;

        float num = 0.f, den = 0.f;
        #pragma unroll
        for (int j = 0; j < 16; ++j) {
            float xk = xs[r][s + 16 * j];   // 16-bank spread, <=4-way: negligible here
            float e  = __builtin_amdgcn_exp2f(fmaf(t, xk, nm2));
            num = fmaf(xk, e, num);
            den += e;
        }
        // reduce the 16 key-slices of this node (lanes s=0..15, group-aligned)
        #pragma unroll
        for (int off = 8; off > 0; off >>= 1) {
            num += __shfl_xor(num, off, 64);
            den += __shfl_xor(den, off, 64);
        }
        if (s == 0) gnode[r][i] = num / den;
    }
    __syncthreads();

    // ---- P3: discrete Chebyshev transform (one wave; 2 rows x 32 coeffs) ----
    if (tid < 2 * KCH) {
        const int r = tid >> 5;
        const int m = tid & 31;
        float acc = 0.f;
        #pragma unroll
        for (int i = 0; i < KCH; ++i) {
            // T_m(tau_i) = cos(pi * m*(2i+1)/64); arg exact in fp32 (<=1953/64)
            float Tmi = cospif((float)(m * (2 * i + 1)) * (1.0f / 64.0f));
            acc = fmaf(gnode[r][i], Tmi, acc);
        }
        coef[r][m] = acc * ((m == 0) ? (1.0f / KCH) : (2.0f / KCH));
        if (m == 0) {
            const int rb = r << 2;
            const float XMAX = fmaxf(fmaxf(red_mx[rb], red_mx[rb+1]), fmaxf(red_mx[rb+2], red_mx[rb+3]));
            const float XMIN = fminf(fminf(red_mn[rb], red_mn[rb+1]), fminf(red_mn[rb+2], red_mn[rb+3]));
            const float c0 = cons[0];
            mids[r]    = fmaf(c0, 0.5f * (XMAX + XMIN), cons[1]);
            float rad  = fabsf(c0) * 0.5f * (XMAX - XMIN);
            radinvs[r] = (rad > 1e-30f) ? (1.0f / rad) : 0.f;   // degenerate row -> tau=0
        }
    }
    __syncthreads();

    // ---- P4: per-query Clenshaw evaluation + row mean ----
    if (tid < ROWS * SEQ) {
        const int r = tid >> 8;
        const int q = tid & 255;
        const float t   = fmaf(cons[0], xs[r][q], cons[1]);
        const float tau = (t - mids[r]) * radinvs[r];   // in [-1,1] exactly
        const float tt  = 2.f * tau;
        float b1 = 0.f, b2 = 0.f;
        #pragma unroll
        for (int m = KCH - 1; m >= 1; --m) {
            float b0 = fmaf(tt, b1, coef[r][m] - b2);   // LDS broadcast reads
            b2 = b1; b1 = b0;
        }
        float g = fmaf(tau, b1, coef[r][0] - b2);

        #pragma unroll
        for (int off = 32; off > 0; off >>= 1) g += __shfl_down(g, off, 64);
        if ((tid & 63) == 0) red_sum[tid >> 6] = g;
    }
    __syncthreads();

    // ---- P5: MLP head, one thread per row ----
    if (tid < ROWS) {
        const int rb = tid << 2;
        float G = (red_sum[rb] + red_sum[rb+1] + red_sum[rb+2] + red_sum[rb+3]) * (1.0f / SEQ);
        float acc = cons[26];
        #pragma unroll
        for (int j = 0; j < 8; ++j) {
            float hv = fmaxf(G * cons[2 + j] + cons[10 + j], 0.f);
            acc += hv * cons[18 + j];
        }
        out[blk * ROWS + tid] = acc;
    }
}

extern "C" void kernel_launch(void* const* d_in, const int* in_sizes, int n_in,
                              void* d_out, int out_size, void* d_ws, size_t ws_size,
                              hipStream_t stream) {
    const float* x     = (const float*)d_in[0];
    const float* emb_w = (const float*)d_in[1];
    const float* emb_b = (const float*)d_in[2];
    const float* q_w   = (const float*)d_in[3];
    const float* q_b   = (const float*)d_in[4];
    const float* k_w   = (const float*)d_in[5];
    const float* k_b   = (const float*)d_in[6];
    const float* v_w   = (const float*)d_in[7];
    const float* v_b   = (const float*)d_in[8];
    const float* f1_w  = (const float*)d_in[9];
    const float* f1_b  = (const float*)d_in[10];
    const float* f2_w  = (const float*)d_in[11];
    const float* f2_b  = (const float*)d_in[12];
    float* out = (float*)d_out;

    const int B = in_sizes[0] / SEQ;   // 1024
    pico_transformer_kernel<<<B / ROWS, NTHREADS, 0, stream>>>(
        x, emb_w, emb_b, q_w, q_b, k_w, k_b, v_w, v_b,
        f1_w, f1_b, f2_w, f2_b, out);
}

// Round 3
// 81.093 us; speedup vs baseline: 1.1494x; 1.0565x over previous
//
#include <hip/hip_runtime.h>

#define SEQ 256
#define ROWS 2                        // batch rows per block
#define KCH 16                        // Chebyshev nodes / terms
#define NTHREADS 1024
#define LOG2E 1.44269504088896340736f

// 16 waves/block; min 8 waves/EU -> VGPR<=64 -> 2 blocks/CU co-resident.
__global__ __launch_bounds__(NTHREADS, 8) void pico_transformer_kernel(
    const float* __restrict__ x,      // [B,S]
    const float* __restrict__ emb_w,  // [4,1]
    const float* __restrict__ emb_b,  // [4]
    const float* __restrict__ q_w,    // [4,4]
    const float* __restrict__ q_b,    // [4]
    const float* __restrict__ k_w,    // [4,4]
    const float* __restrict__ k_b,    // [4]
    const float* __restrict__ v_w,    // [4,4]
    const float* __restrict__ v_b,    // [4]
    const float* __restrict__ f1_w,   // [8,4]
    const float* __restrict__ f1_b,   // [8]
    const float* __restrict__ f2_w,   // [1,8]
    const float* __restrict__ f2_b,   // [1]
    float* __restrict__ out)          // [B]
{
    __shared__ float xs[ROWS][SEQ];
    __shared__ float cons[27];  // [0]=a(log2) [1]=b(log2) [2..9]=u [10..17]=w [18..25]=f2w [26]=f2b
    __shared__ float red_mx[8], red_mn[8];      // per-wave row min/max partials
    __shared__ float gnode[ROWS][KCH];          // g at Chebyshev nodes
    __shared__ float coef[ROWS][KCH];           // Chebyshev coefficients (scaled)
    __shared__ float red_sum[8];

    const int tid = threadIdx.x;
    const int blk = blockIdx.x;

    // ---- P1: stage 2 rows of x + per-row min/max; waves 0-7 ----
    if (tid < ROWS * SEQ) {
        const int r   = tid >> 8;
        const int col = tid & 255;
        float xv = x[(blk * ROWS + r) * SEQ + col];
        xs[r][col] = xv;
        float mx = xv, mn = xv;
        #pragma unroll
        for (int off = 32; off > 0; off >>= 1) {
            mx = fmaxf(mx, __shfl_down(mx, off, 64));
            mn = fminf(mn, __shfl_down(mn, off, 64));
        }
        if ((tid & 63) == 0) { red_mx[tid >> 6] = mx; red_mn[tid >> 6] = mn; }
    }

    // ---- Weight fold, parallel over 8 lanes of wave 0 ----
    // Lane j folds the V path + FFN column j (redundant tiny 4x4 matvec);
    // lane 0 additionally folds the Q/K path into the temperature affine.
    if (tid < 8) {
        const int j = tid;
        float we[4], be[4], Av[4], Bv[4];
        #pragma unroll
        for (int d = 0; d < 4; ++d) { we[d] = emb_w[d]; be[d] = emb_b[d]; }
        #pragma unroll
        for (int e = 0; e < 4; ++e) {
            float av = 0.f, bv = 0.f;
            #pragma unroll
            for (int d = 0; d < 4; ++d) {
                av += v_w[e*4+d] * we[d];
                bv += v_w[e*4+d] * be[d];
            }
            Av[e] = av; Bv[e] = bv + v_b[e];
        }
        float u = 0.f, w = 0.f;
        #pragma unroll
        for (int d = 0; d < 4; ++d) {
            u += f1_w[j*4+d] * Av[d];
            w += f1_w[j*4+d] * Bv[d];
        }
        cons[2 + j]  = u;
        cons[10 + j] = w + f1_b[j];
        cons[18 + j] = f2_w[j];
        if (j == 0) {
            float Aq[4], Bq[4], Ak[4];
            #pragma unroll
            for (int e = 0; e < 4; ++e) {
                float aq = 0.f, bq = 0.f, ak = 0.f;
                #pragma unroll
                for (int d = 0; d < 4; ++d) {
                    aq += q_w[e*4+d] * we[d];
                    bq += q_w[e*4+d] * be[d];
                    ak += k_w[e*4+d] * we[d];
                }
                Aq[e] = aq; Bq[e] = bq + q_b[e]; Ak[e] = ak;
            }
            float c1 = 0.f, c3 = 0.f;
            #pragma unroll
            for (int d = 0; d < 4; ++d) { c1 += Aq[d]*Ak[d]; c3 += Bq[d]*Ak[d]; }
            cons[0]  = 0.5f * c1 * LOG2E;   // temperature slope (log2 domain)
            cons[1]  = 0.5f * c3 * LOG2E;   // temperature offset
            cons[26] = f2_b[0];
        }
    }

    __syncthreads();  // xs, cons, red_mx/red_mn

    // ---- P2: g(t) exactly at 16 Chebyshev-Gauss nodes per row ----
    // thread -> (row r, node i, key-slice s in 0..31): 8 keys per thread.
    {
        const int r = tid >> 9;
        const int i = (tid >> 5) & 15;
        const int s = tid & 31;

        const int rb = r << 2;
        const float XMAX = fmaxf(fmaxf(red_mx[rb], red_mx[rb+1]), fmaxf(red_mx[rb+2], red_mx[rb+3]));
        const float XMIN = fminf(fminf(red_mn[rb], red_mn[rb+1]), fminf(red_mn[rb+2], red_mn[rb+3]));

        const float c0  = cons[0], c1v = cons[1];
        const float mid = fmaf(c0, 0.5f * (XMAX + XMIN), c1v);
        const float rad = fabsf(c0) * 0.5f * (XMAX - XMIN);

        // node temperature t_i = mid + rad*cos(pi*(2i+1)/32)
        const float tau_i = cospif((float)(2 * i + 1) * (1.0f / 32.0f));
        const float t     = fmaf(rad, tau_i, mid);
        const float m2    = (t >= 0.f) ? t * XMAX : t * XMIN;  // exact row max of t*x
        const float nm2   = -m2;

        float num = 0.f, den = 0.f;
        #pragma unroll
        for (int j = 0; j < 8; ++j) {
            float xk = xs[r][s + 32 * j];   // lanes 0-31 hit distinct banks; 32-63 broadcast
            float e  = __builtin_amdgcn_exp2f(fmaf(t, xk, nm2));
            num = fmaf(xk, e, num);
            den += e;
        }
        // reduce the 32 key-slices of this node (lanes s=0..31, group-aligned)
        #pragma unroll
        for (int off = 16; off > 0; off >>= 1) {
            num += __shfl_xor(num, off, 64);
            den += __shfl_xor(den, off, 64);
        }
        if (s == 0) gnode[r][i] = num / den;
    }
    __syncthreads();

    // ---- P3: Chebyshev transform, fully parallel: thread=(r,m,i) ----
    if (tid < ROWS * KCH * KCH) {   // 512
        const int r = tid >> 8;
        const int m = (tid >> 4) & 15;
        const int i = tid & 15;
        // T_m(tau_i) = cos(pi*m*(2i+1)/32); arg exact in fp32 (multiple of 1/32)
        float Tmi  = cospif((float)(m * (2 * i + 1)) * (1.0f / 32.0f));
        float prod = gnode[r][i] * Tmi;
        #pragma unroll
        for (int off = 8; off > 0; off >>= 1) prod += __shfl_xor(prod, off, 64);
        if (i == 0) coef[r][m] = prod * ((m == 0) ? (1.0f / KCH) : (2.0f / KCH));
    }
    __syncthreads();

    // ---- P4: per-query Clenshaw evaluation + row mean; waves 0-7 ----
    if (tid < ROWS * SEQ) {
        const int r = tid >> 8;
        const int q = tid & 255;
        const int rb = r << 2;
        const float XMAX = fmaxf(fmaxf(red_mx[rb], red_mx[rb+1]), fmaxf(red_mx[rb+2], red_mx[rb+3]));
        const float XMIN = fminf(fminf(red_mn[rb], red_mn[rb+1]), fminf(red_mn[rb+2], red_mn[rb+3]));
        const float c0  = cons[0];
        const float mid = fmaf(c0, 0.5f * (XMAX + XMIN), cons[1]);
        const float rad = fabsf(c0) * 0.5f * (XMAX - XMIN);
        const float radinv = (rad > 1e-30f) ? (1.0f / rad) : 0.f;  // degenerate row -> tau=0

        const float t   = fmaf(c0, xs[r][q], cons[1]);
        const float tau = (t - mid) * radinv;   // in [-1,1] by construction
        const float tt  = 2.f * tau;
        float b1 = 0.f, b2 = 0.f;
        #pragma unroll
        for (int m = KCH - 1; m >= 1; --m) {
            float b0 = fmaf(tt, b1, coef[r][m] - b2);   // LDS broadcast reads
            b2 = b1; b1 = b0;
        }
        float g = fmaf(tau, b1, coef[r][0] - b2);

        #pragma unroll
        for (int off = 32; off > 0; off >>= 1) g += __shfl_down(g, off, 64);
        if ((tid & 63) == 0) red_sum[tid >> 6] = g;
    }
    __syncthreads();

    // ---- P5: MLP head, one thread per row ----
    if (tid < ROWS) {
        const int rb = tid << 2;
        float G = (red_sum[rb] + red_sum[rb+1] + red_sum[rb+2] + red_sum[rb+3]) * (1.0f / SEQ);
        float acc = cons[26];
        #pragma unroll
        for (int j = 0; j < 8; ++j) {
            float hv = fmaxf(G * cons[2 + j] + cons[10 + j], 0.f);
            acc += hv * cons[18 + j];
        }
        out[blk * ROWS + tid] = acc;
    }
}

extern "C" void kernel_launch(void* const* d_in, const int* in_sizes, int n_in,
                              void* d_out, int out_size, void* d_ws, size_t ws_size,
                              hipStream_t stream) {
    const float* x     = (const float*)d_in[0];
    const float* emb_w = (const float*)d_in[1];
    const float* emb_b = (const float*)d_in[2];
    const float* q_w   = (const float*)d_in[3];
    const float* q_b   = (const float*)d_in[4];
    const float* k_w   = (const float*)d_in[5];
    const float* k_b   = (const float*)d_in[6];
    const float* v_w   = (const float*)d_in[7];
    const float* v_b   = (const float*)d_in[8];
    const float* f1_w  = (const float*)d_in[9];
    const float* f1_b  = (const float*)d_in[10];
    const float* f2_w  = (const float*)d_in[11];
    const float* f2_b  = (const float*)d_in[12];
    float* out = (float*)d_out;

    const int B = in_sizes[0] / SEQ;   // 1024
    pico_transformer_kernel<<<B / ROWS, NTHREADS, 0, stream>>>(
        x, emb_w, emb_b, q_w, q_b, k_w, k_b, v_w, v_b,
        f1_w, f1_b, f2_w, f2_b, out);
}